// Round 1
// baseline (561.497 us; speedup 1.0000x reference)
//
#include <hip/hip_runtime.h>
#include <hip/hip_bf16.h>
#include <cstdint>

#define B_  4
#define N_  4096
#define C_  256
#define CD_ 64

typedef unsigned short ushort_t;
typedef __bf16 bf16x8 __attribute__((ext_vector_type(8)));
typedef float f32x4 __attribute__((ext_vector_type(4)));

// (1/sqrt(256)) * log2(e): folded into K projection so S' = S_true * log2(e)
static constexpr float SCALE_LOG2E = 0.09016844005556021f;

__device__ __forceinline__ ushort_t f2bf(float x) {
    union { float f; unsigned u; } v; v.f = x;
    unsigned u = v.u;
    unsigned r = (u + 0x7fffu + ((u >> 16) & 1u)) >> 16;  // round-nearest-even
    return (ushort_t)r;
}

__device__ __forceinline__ bf16x8 ld_bf8(const ushort_t* p) {
    return *reinterpret_cast<const bf16x8*>(p);
}

// ---------------------------------------------------------------------------
// Projection producing TRANSPOSED bf16 output dst[b][n][o]  (for Qt, Kt)
// dst = (W @ X + bias) * outScale
// ---------------------------------------------------------------------------
__global__ void proj_t_kernel(const float* __restrict__ X, const float* __restrict__ W,
                              const float* __restrict__ bias, ushort_t* __restrict__ dst,
                              int Cin, float outScale) {
    __shared__ float sX[16][68];
    __shared__ float sW[64][17];
    const int tid = threadIdx.x;
    const int b = blockIdx.z;
    const int oBase = blockIdx.y * 64;
    const int nBase = blockIdx.x * 64;
    const int tx = tid & 15, ty = tid >> 4;
    float acc[4][4] = {};
    for (int k0 = 0; k0 < Cin; k0 += 16) {
        int kk = tid >> 4, nn = (tid & 15) * 4;
        float4 xv = *(const float4*)(X + ((size_t)b * Cin + k0 + kk) * N_ + nBase + nn);
        *(float4*)&sX[kk][nn] = xv;
        int oo = tid >> 2, kc = (tid & 3) * 4;
        float4 wv = *(const float4*)(W + (size_t)(oBase + oo) * Cin + k0 + kc);
        sW[oo][kc + 0] = wv.x; sW[oo][kc + 1] = wv.y;
        sW[oo][kc + 2] = wv.z; sW[oo][kc + 3] = wv.w;
        __syncthreads();
#pragma unroll
        for (int kk2 = 0; kk2 < 16; ++kk2) {
            float4 xr4 = *(float4*)&sX[kk2][tx * 4];
            float xr[4] = {xr4.x, xr4.y, xr4.z, xr4.w};
#pragma unroll
            for (int i = 0; i < 4; ++i) {
                float wv2 = sW[ty * 4 + i][kk2];
#pragma unroll
                for (int j = 0; j < 4; ++j) acc[i][j] += wv2 * xr[j];
            }
        }
        __syncthreads();
    }
    float4 bi4 = *(const float4*)(bias + oBase + ty * 4);
    float bia[4] = {bi4.x, bi4.y, bi4.z, bi4.w};
#pragma unroll
    for (int j = 0; j < 4; ++j) {
        int n = nBase + tx * 4 + j;
        unsigned p0 = f2bf((acc[0][j] + bia[0]) * outScale);
        unsigned p1 = f2bf((acc[1][j] + bia[1]) * outScale);
        unsigned p2 = f2bf((acc[2][j] + bia[2]) * outScale);
        unsigned p3 = f2bf((acc[3][j] + bia[3]) * outScale);
        uint2 pk; pk.x = p0 | (p1 << 16); pk.y = p2 | (p3 << 16);
        *(uint2*)(dst + ((size_t)b * N_ + n) * C_ + oBase + ty * 4) = pk;
    }
}

// ---------------------------------------------------------------------------
// Projection producing NATURAL bf16 output dst[b][o][n]  (for V)
// ---------------------------------------------------------------------------
__global__ void proj_n_kernel(const float* __restrict__ X, const float* __restrict__ W,
                              const float* __restrict__ bias, ushort_t* __restrict__ dst,
                              int Cin) {
    __shared__ float sX[16][68];
    __shared__ float sW[64][17];
    const int tid = threadIdx.x;
    const int b = blockIdx.z;
    const int oBase = blockIdx.y * 64;
    const int nBase = blockIdx.x * 64;
    const int tx = tid & 15, ty = tid >> 4;
    float acc[4][4] = {};
    for (int k0 = 0; k0 < Cin; k0 += 16) {
        int kk = tid >> 4, nn = (tid & 15) * 4;
        float4 xv = *(const float4*)(X + ((size_t)b * Cin + k0 + kk) * N_ + nBase + nn);
        *(float4*)&sX[kk][nn] = xv;
        int oo = tid >> 2, kc = (tid & 3) * 4;
        float4 wv = *(const float4*)(W + (size_t)(oBase + oo) * Cin + k0 + kc);
        sW[oo][kc + 0] = wv.x; sW[oo][kc + 1] = wv.y;
        sW[oo][kc + 2] = wv.z; sW[oo][kc + 3] = wv.w;
        __syncthreads();
#pragma unroll
        for (int kk2 = 0; kk2 < 16; ++kk2) {
            float4 xr4 = *(float4*)&sX[kk2][tx * 4];
            float xr[4] = {xr4.x, xr4.y, xr4.z, xr4.w};
#pragma unroll
            for (int i = 0; i < 4; ++i) {
                float wv2 = sW[ty * 4 + i][kk2];
#pragma unroll
                for (int j = 0; j < 4; ++j) acc[i][j] += wv2 * xr[j];
            }
        }
        __syncthreads();
    }
#pragma unroll
    for (int i = 0; i < 4; ++i) {
        int o = oBase + ty * 4 + i;
        float bia = bias[o];
        unsigned p0 = f2bf(acc[i][0] + bia);
        unsigned p1 = f2bf(acc[i][1] + bia);
        unsigned p2 = f2bf(acc[i][2] + bia);
        unsigned p3 = f2bf(acc[i][3] + bia);
        uint2 pk; pk.x = p0 | (p1 << 16); pk.y = p2 | (p3 << 16);
        *(uint2*)(dst + ((size_t)b * C_ + o) * N_ + nBase + tx * 4) = pk;
    }
}

// ---------------------------------------------------------------------------
// Pass A: l[b][i] = sum_j exp(S_true[i][j])  (S' in log2 domain, no max)
// grid (N/64, 4 j-slices, B), block 256 (4 waves x 16 rows)
// ---------------------------------------------------------------------------
__global__ void stats_kernel(const ushort_t* __restrict__ Kt, const ushort_t* __restrict__ Qt,
                             float* __restrict__ l) {
    const int tid = threadIdx.x;
    const int w = tid >> 6, lane = tid & 63, g = lane >> 4, c16 = lane & 15;
    const int b = blockIdx.z;
    const int ib = blockIdx.x * 64 + w * 16;       // this wave's 16 rows
    const int j0 = blockIdx.y * 1024;              // j slice
    const size_t ktb = ((size_t)b * N_ + ib + c16) * C_ + g * 8;
    bf16x8 ka[8];
#pragma unroll
    for (int k = 0; k < 8; ++k) ka[k] = ld_bf8(Kt + ktb + k * 32);
    float lsum[4] = {0.f, 0.f, 0.f, 0.f};
    for (int jt = 0; jt < 1024; jt += 16) {
        const size_t qb_base = ((size_t)b * N_ + j0 + jt + c16) * C_ + g * 8;
        f32x4 d = {0.f, 0.f, 0.f, 0.f};
#pragma unroll
        for (int k = 0; k < 8; ++k) {
            bf16x8 qb = ld_bf8(Qt + qb_base + k * 32);
            d = __builtin_amdgcn_mfma_f32_16x16x32_bf16(ka[k], qb, d, 0, 0, 0);
        }
#pragma unroll
        for (int r = 0; r < 4; ++r) lsum[r] += exp2f(d[r]);
    }
#pragma unroll
    for (int r = 0; r < 4; ++r) {
        float s = lsum[r];
        s += __shfl_xor(s, 1, 64);
        s += __shfl_xor(s, 2, 64);
        s += __shfl_xor(s, 4, 64);
        s += __shfl_xor(s, 8, 64);
        if (c16 == 0) atomicAdd(l + (size_t)b * N_ + ib + g * 4 + r, s);
    }
}

// ---------------------------------------------------------------------------
// Pass B: O[c][j] += sum_i V[c][i] * exp2(S'[i][j] - log2 l_i); atomic into
// d_out which is pre-initialized with x_s2 (residual).
// grid (N/64 j-tiles, 2 i-halves, B), block 512 (8 waves)
// ---------------------------------------------------------------------------
__global__ void out_kernel(const ushort_t* __restrict__ Kt, const ushort_t* __restrict__ Qt,
                           const ushort_t* __restrict__ V, const float* __restrict__ l,
                           float* __restrict__ dout) {
    __shared__ ushort_t sQ[64][264];   // Qt j-tile [jloc][c], staged once
    __shared__ ushort_t sP[64][72];    // P^T [jloc][iloc], +8 pad
    __shared__ float sr[64];           // log2(l) for current i-chunk
    const int tid = threadIdx.x;
    const int w = tid >> 6, lane = tid & 63, g = lane >> 4, c16 = lane & 15;
    const int b = blockIdx.z;
    const int jb = blockIdx.x * 64;
    const int ibase = blockIdx.y * 2048;
    // stage Qt tile: 64 rows x 256 c bf16
    {
        int jl = tid >> 3, cp = (tid & 7) * 32;
        const ushort_t* src = Qt + ((size_t)b * N_ + jb + jl) * C_ + cp;
        uint4 a0 = *(const uint4*)(src);
        uint4 a1 = *(const uint4*)(src + 8);
        uint4 a2 = *(const uint4*)(src + 16);
        uint4 a3 = *(const uint4*)(src + 24);
        *(uint4*)&sQ[jl][cp + 0]  = a0;
        *(uint4*)&sQ[jl][cp + 8]  = a1;
        *(uint4*)&sQ[jl][cp + 16] = a2;
        *(uint4*)&sQ[jl][cp + 24] = a3;
    }
    f32x4 acc[2][4];
#pragma unroll
    for (int mt = 0; mt < 2; ++mt)
#pragma unroll
        for (int nt = 0; nt < 4; ++nt) acc[mt][nt] = (f32x4){0.f, 0.f, 0.f, 0.f};

    const int isub = (w & 3) * 16;   // S-phase: wave's i rows within chunk
    const int jh = (w >> 2) * 32;    // S-phase: wave's j half
    const int cb = w * 32;           // PV-phase: wave's c rows

    for (int ic = 0; ic < 32; ++ic) {
        const int i0 = ibase + ic * 64;
        if (tid < 64) sr[tid] = log2f(l[(size_t)b * N_ + i0 + tid]);
        __syncthreads();  // sr ready; prev chunk's PV done -> sP free
        // ---- S phase: compute P strip, write transposed to LDS ----
        const size_t ktb = ((size_t)b * N_ + i0 + isub + c16) * C_ + g * 8;
        bf16x8 ka[8];
#pragma unroll
        for (int k = 0; k < 8; ++k) ka[k] = ld_bf8(Kt + ktb + k * 32);
        float rv[4];
#pragma unroll
        for (int r = 0; r < 4; ++r) rv[r] = sr[isub + g * 4 + r];
#pragma unroll
        for (int nt = 0; nt < 2; ++nt) {
            const int jl = jh + nt * 16;
            f32x4 d = {0.f, 0.f, 0.f, 0.f};
#pragma unroll
            for (int k = 0; k < 8; ++k) {
                bf16x8 qb = *reinterpret_cast<const bf16x8*>(&sQ[jl + c16][k * 32 + g * 8]);
                d = __builtin_amdgcn_mfma_f32_16x16x32_bf16(ka[k], qb, d, 0, 0, 0);
            }
            unsigned p0 = f2bf(exp2f(d[0] - rv[0]));
            unsigned p1 = f2bf(exp2f(d[1] - rv[1]));
            unsigned p2 = f2bf(exp2f(d[2] - rv[2]));
            unsigned p3 = f2bf(exp2f(d[3] - rv[3]));
            uint2 pk; pk.x = p0 | (p1 << 16); pk.y = p2 | (p3 << 16);
            *(uint2*)&sP[jl + c16][isub + g * 4] = pk;
        }
        __syncthreads();  // sP ready
        // ---- PV phase ----
#pragma unroll
        for (int ks = 0; ks < 2; ++ks) {
            bf16x8 va[2];
#pragma unroll
            for (int mt = 0; mt < 2; ++mt)
                va[mt] = ld_bf8(V + ((size_t)b * C_ + cb + mt * 16 + c16) * N_ + i0 + ks * 32 + g * 8);
#pragma unroll
            for (int nt = 0; nt < 4; ++nt) {
                bf16x8 pb = *reinterpret_cast<const bf16x8*>(&sP[nt * 16 + c16][ks * 32 + g * 8]);
#pragma unroll
                for (int mt = 0; mt < 2; ++mt)
                    acc[mt][nt] = __builtin_amdgcn_mfma_f32_16x16x32_bf16(va[mt], pb, acc[mt][nt], 0, 0, 0);
            }
        }
        // next iteration's barrier (after sr write) protects sP overwrite
    }
#pragma unroll
    for (int mt = 0; mt < 2; ++mt)
#pragma unroll
        for (int nt = 0; nt < 4; ++nt)
#pragma unroll
            for (int r = 0; r < 4; ++r) {
                int c = cb + mt * 16 + g * 4 + r;
                int j = jb + nt * 16 + c16;
                atomicAdd(dout + ((size_t)b * C_ + c) * N_ + j, acc[mt][nt][r]);
            }
}

extern "C" void kernel_launch(void* const* d_in, const int* in_sizes, int n_in,
                              void* d_out, int out_size, void* d_ws, size_t ws_size,
                              hipStream_t stream) {
    const float* x_s2  = (const float*)d_in[0];
    const float* x_dem = (const float*)d_in[1];
    const float* Wq = (const float*)d_in[2];
    const float* bq = (const float*)d_in[3];
    const float* Wk = (const float*)d_in[4];
    const float* bk = (const float*)d_in[5];
    const float* Wv = (const float*)d_in[6];
    const float* bv = (const float*)d_in[7];
    float* out = (float*)d_out;

    char* ws = (char*)d_ws;
    ushort_t* Qt = (ushort_t*)(ws);                               // [B][N][C] bf16, 8 MB
    ushort_t* Kt = (ushort_t*)(ws + (size_t)8  * 1024 * 1024);    // [B][N][C] bf16, pre-scaled
    ushort_t* Vm = (ushort_t*)(ws + (size_t)16 * 1024 * 1024);    // [B][C][N] bf16
    float*    lv = (float*)   (ws + (size_t)24 * 1024 * 1024);    // [B][N] row sums

    hipMemsetAsync(lv, 0, (size_t)B_ * N_ * sizeof(float), stream);
    // residual: pre-fill output with x_s2; out_kernel atomically adds O
    hipMemcpyAsync(out, x_s2, (size_t)B_ * C_ * N_ * sizeof(float),
                   hipMemcpyDeviceToDevice, stream);

    proj_t_kernel<<<dim3(N_ / 64, C_ / 64, B_), 256, 0, stream>>>(x_s2, Wq, bq, Qt, C_, 1.0f);
    proj_t_kernel<<<dim3(N_ / 64, C_ / 64, B_), 256, 0, stream>>>(x_dem, Wk, bk, Kt, CD_, SCALE_LOG2E);
    proj_n_kernel<<<dim3(N_ / 64, C_ / 64, B_), 256, 0, stream>>>(x_dem, Wv, bv, Vm, CD_);
    stats_kernel<<<dim3(N_ / 64, 4, B_), 256, 0, stream>>>(Kt, Qt, lv);
    out_kernel<<<dim3(N_ / 64, 2, B_), 512, 0, stream>>>(Kt, Qt, Vm, lv, out);
}

// Round 2
// 362.542 us; speedup vs baseline: 1.5488x; 1.5488x over previous
//
#include <hip/hip_runtime.h>
#include <hip/hip_bf16.h>
#include <cstdint>

#define B_  4
#define N_  4096
#define C_  256
#define CD_ 64

typedef unsigned short ushort_t;
typedef __bf16 bf16x8 __attribute__((ext_vector_type(8)));
typedef float f32x4 __attribute__((ext_vector_type(4)));

typedef const __attribute__((address_space(1))) void* gas_t;
typedef __attribute__((address_space(3))) void* las_t;

// (1/sqrt(256)) * log2(e): folded into K projection so S' = S_true * log2(e)
static constexpr float SCALE_LOG2E = 0.09016844005556021f;

__device__ __forceinline__ ushort_t f2bf(float x) {
    union { float f; unsigned u; } v; v.f = x;
    unsigned u = v.u;
    unsigned r = (u + 0x7fffu + ((u >> 16) & 1u)) >> 16;  // round-nearest-even
    return (ushort_t)r;
}

__device__ __forceinline__ bf16x8 ld_bf8(const ushort_t* p) {
    return *reinterpret_cast<const bf16x8*>(p);
}

// ---------------------------------------------------------------------------
// Projection producing TRANSPOSED bf16 output dst[b][n][o]  (for Qt, Kt)
// dst = (W @ X + bias) * outScale      (unchanged from R1 — proven correct)
// ---------------------------------------------------------------------------
__global__ void proj_t_kernel(const float* __restrict__ X, const float* __restrict__ W,
                              const float* __restrict__ bias, ushort_t* __restrict__ dst,
                              int Cin, float outScale) {
    __shared__ float sX[16][68];
    __shared__ float sW[64][17];
    const int tid = threadIdx.x;
    const int b = blockIdx.z;
    const int oBase = blockIdx.y * 64;
    const int nBase = blockIdx.x * 64;
    const int tx = tid & 15, ty = tid >> 4;
    float acc[4][4] = {};
    for (int k0 = 0; k0 < Cin; k0 += 16) {
        int kk = tid >> 4, nn = (tid & 15) * 4;
        float4 xv = *(const float4*)(X + ((size_t)b * Cin + k0 + kk) * N_ + nBase + nn);
        *(float4*)&sX[kk][nn] = xv;
        int oo = tid >> 2, kc = (tid & 3) * 4;
        float4 wv = *(const float4*)(W + (size_t)(oBase + oo) * Cin + k0 + kc);
        sW[oo][kc + 0] = wv.x; sW[oo][kc + 1] = wv.y;
        sW[oo][kc + 2] = wv.z; sW[oo][kc + 3] = wv.w;
        __syncthreads();
#pragma unroll
        for (int kk2 = 0; kk2 < 16; ++kk2) {
            float4 xr4 = *(float4*)&sX[kk2][tx * 4];
            float xr[4] = {xr4.x, xr4.y, xr4.z, xr4.w};
#pragma unroll
            for (int i = 0; i < 4; ++i) {
                float wv2 = sW[ty * 4 + i][kk2];
#pragma unroll
                for (int j = 0; j < 4; ++j) acc[i][j] += wv2 * xr[j];
            }
        }
        __syncthreads();
    }
    float4 bi4 = *(const float4*)(bias + oBase + ty * 4);
    float bia[4] = {bi4.x, bi4.y, bi4.z, bi4.w};
#pragma unroll
    for (int j = 0; j < 4; ++j) {
        int n = nBase + tx * 4 + j;
        unsigned p0 = f2bf((acc[0][j] + bia[0]) * outScale);
        unsigned p1 = f2bf((acc[1][j] + bia[1]) * outScale);
        unsigned p2 = f2bf((acc[2][j] + bia[2]) * outScale);
        unsigned p3 = f2bf((acc[3][j] + bia[3]) * outScale);
        uint2 pk; pk.x = p0 | (p1 << 16); pk.y = p2 | (p3 << 16);
        *(uint2*)(dst + ((size_t)b * N_ + n) * C_ + oBase + ty * 4) = pk;
    }
}

// ---------------------------------------------------------------------------
// Projection producing NATURAL bf16 output dst[b][o][n]  (for V) — unchanged
// ---------------------------------------------------------------------------
__global__ void proj_n_kernel(const float* __restrict__ X, const float* __restrict__ W,
                              const float* __restrict__ bias, ushort_t* __restrict__ dst,
                              int Cin) {
    __shared__ float sX[16][68];
    __shared__ float sW[64][17];
    const int tid = threadIdx.x;
    const int b = blockIdx.z;
    const int oBase = blockIdx.y * 64;
    const int nBase = blockIdx.x * 64;
    const int tx = tid & 15, ty = tid >> 4;
    float acc[4][4] = {};
    for (int k0 = 0; k0 < Cin; k0 += 16) {
        int kk = tid >> 4, nn = (tid & 15) * 4;
        float4 xv = *(const float4*)(X + ((size_t)b * Cin + k0 + kk) * N_ + nBase + nn);
        *(float4*)&sX[kk][nn] = xv;
        int oo = tid >> 2, kc = (tid & 3) * 4;
        float4 wv = *(const float4*)(W + (size_t)(oBase + oo) * Cin + k0 + kc);
        sW[oo][kc + 0] = wv.x; sW[oo][kc + 1] = wv.y;
        sW[oo][kc + 2] = wv.z; sW[oo][kc + 3] = wv.w;
        __syncthreads();
#pragma unroll
        for (int kk2 = 0; kk2 < 16; ++kk2) {
            float4 xr4 = *(float4*)&sX[kk2][tx * 4];
            float xr[4] = {xr4.x, xr4.y, xr4.z, xr4.w};
#pragma unroll
            for (int i = 0; i < 4; ++i) {
                float wv2 = sW[ty * 4 + i][kk2];
#pragma unroll
                for (int j = 0; j < 4; ++j) acc[i][j] += wv2 * xr[j];
            }
        }
        __syncthreads();
    }
#pragma unroll
    for (int i = 0; i < 4; ++i) {
        int o = oBase + ty * 4 + i;
        float bia = bias[o];
        unsigned p0 = f2bf(acc[i][0] + bia);
        unsigned p1 = f2bf(acc[i][1] + bia);
        unsigned p2 = f2bf(acc[i][2] + bia);
        unsigned p3 = f2bf(acc[i][3] + bia);
        uint2 pk; pk.x = p0 | (p1 << 16); pk.y = p2 | (p3 << 16);
        *(uint2*)(dst + ((size_t)b * C_ + o) * N_ + nBase + tx * 4) = pk;
    }
}

// ---------------------------------------------------------------------------
// Pass A v2: l[b][i] = sum_j exp2(S'[i][j]).  m97-style GEMM:
// 128x128 tile / block, BK=64, global_load_lds(16B) staging with XOR-swizzled
// source chunks (global_load_lds forbids padding; swizzle kills the 16-way
// row-aligned bank conflict, residual 2-way is free per m136).
// grid (32 j-tiles, 32 i-tiles, B), block 256 (4 waves, 2x2 of 64x64).
// ---------------------------------------------------------------------------
__global__ __launch_bounds__(256, 3)
void stats_kernel(const ushort_t* __restrict__ Kt, const ushort_t* __restrict__ Qt,
                  float* __restrict__ l) {
    __shared__ ushort_t sA[128 * 64];   // [row i][8 chunks of 8 bf16, swizzled]
    __shared__ ushort_t sB[128 * 64];   // [row j][...]
    const int tid = threadIdx.x;
    const int lane = tid & 63, g = lane >> 4, c16 = lane & 15;
    const int w = tid >> 6, wi = w >> 1, wj = w & 1;
    const int b = blockIdx.z;
    const int ib = blockIdx.y * 128, jb = blockIdx.x * 128;
    f32x4 acc[4][4];
#pragma unroll
    for (int mt = 0; mt < 4; ++mt)
#pragma unroll
        for (int nt = 0; nt < 4; ++nt) acc[mt][nt] = (f32x4){0.f, 0.f, 0.f, 0.f};

    const int srow = tid >> 3;     // 0..31, round q adds q*32
    const int sc4 = tid & 7;       // destination chunk slot within row

    for (int k0 = 0; k0 < 256; k0 += 64) {
#pragma unroll
        for (int q = 0; q < 4; ++q) {
            const int row = q * 32 + srow;
            const int gc = sc4 ^ (row & 7);                 // swizzled source chunk
            const ushort_t* srcA = Kt + ((size_t)(b * N_ + ib + row)) * C_ + k0 + gc * 8;
            const ushort_t* srcB = Qt + ((size_t)(b * N_ + jb + row)) * C_ + k0 + gc * 8;
            __builtin_amdgcn_global_load_lds((gas_t)srcA, (las_t)&sA[(q * 256 + tid) * 8], 16, 0, 0);
            __builtin_amdgcn_global_load_lds((gas_t)srcB, (las_t)&sB[(q * 256 + tid) * 8], 16, 0, 0);
        }
        __syncthreads();
#pragma unroll
        for (int ks = 0; ks < 2; ++ks) {
            bf16x8 af[4], bf[4];
#pragma unroll
            for (int mt = 0; mt < 4; ++mt) {
                const int row = wi * 64 + mt * 16 + c16;
                af[mt] = *(const bf16x8*)&sA[row * 64 + (((ks * 4 + g) ^ (row & 7)) * 8)];
            }
#pragma unroll
            for (int nt = 0; nt < 4; ++nt) {
                const int row = wj * 64 + nt * 16 + c16;
                bf[nt] = *(const bf16x8*)&sB[row * 64 + (((ks * 4 + g) ^ (row & 7)) * 8)];
            }
#pragma unroll
            for (int mt = 0; mt < 4; ++mt)
#pragma unroll
                for (int nt = 0; nt < 4; ++nt)
                    acc[mt][nt] = __builtin_amdgcn_mfma_f32_16x16x32_bf16(af[mt], bf[nt], acc[mt][nt], 0, 0, 0);
        }
        __syncthreads();
    }
    // epilogue: e = exp2(S'), row-sum over 128 j of this block, atomic into l
#pragma unroll
    for (int mt = 0; mt < 4; ++mt) {
#pragma unroll
        for (int r = 0; r < 4; ++r) {
            float s = exp2f(acc[mt][0][r]) + exp2f(acc[mt][1][r])
                    + exp2f(acc[mt][2][r]) + exp2f(acc[mt][3][r]);
            s += __shfl_xor(s, 1, 64);
            s += __shfl_xor(s, 2, 64);
            s += __shfl_xor(s, 4, 64);
            s += __shfl_xor(s, 8, 64);
            if (c16 == 0)
                atomicAdd(l + (size_t)b * N_ + ib + wi * 64 + mt * 16 + g * 4 + r, s);
        }
    }
}

// ---------------------------------------------------------------------------
// Pass B v2: O[c][j] += sum_i V[c][i] * exp2(S'[i][j] - log2 l_i).
// Block = 64 j x all 256 c, i-chunk = 128, 8 waves.
//   S phase : wave w computes rows i = w*16..+16 x all 64 j (K=256 from
//             swizzle-staged sQ; Kt A-frags straight from global/L2).
//   P^T goes to swizzled sP[64 j][128 i]; PV phase: wave w owns c = w*32..+32.
// grid (64 j-tiles, 2 i-halves, B), block 512; atomics onto residual-prefilled
// d_out.
// ---------------------------------------------------------------------------
__global__ __launch_bounds__(512, 4)
void out_kernel(const ushort_t* __restrict__ Kt, const ushort_t* __restrict__ Qt,
                const ushort_t* __restrict__ V, const float* __restrict__ l,
                float* __restrict__ dout) {
    __shared__ ushort_t sQ[64 * 256];   // [j][32 chunks of 8 bf16, swizzled] 32 KB
    __shared__ ushort_t sP[64 * 128];   // [j][16 chunks of 8 bf16, swizzled] 16 KB
    __shared__ float sl[128];
    const int tid = threadIdx.x;
    const int w = tid >> 6, lane = tid & 63, g = lane >> 4, c16 = lane & 15;
    const int b = blockIdx.z;
    const int jb = blockIdx.x * 64;
    const int ibase = blockIdx.y * 2048;

    // stage Qt j-tile once, XOR-swizzled chunks (chunk ^ (row&7))
    {
        const int jl = tid >> 3, tc = (tid & 7) * 4;
        const ushort_t* src = Qt + ((size_t)(b * N_ + jb + jl)) * C_;
#pragma unroll
        for (int q = 0; q < 4; ++q) {
            const int ch = tc + q;
            uint4 v = *(const uint4*)(src + ch * 8);
            *(uint4*)&sQ[jl * 256 + ((ch ^ (jl & 7)) * 8)] = v;
        }
    }
    f32x4 acc[2][4];
#pragma unroll
    for (int mt = 0; mt < 2; ++mt)
#pragma unroll
        for (int nt = 0; nt < 4; ++nt) acc[mt][nt] = (f32x4){0.f, 0.f, 0.f, 0.f};

    const int iw = w * 16;    // S-phase i rows within chunk
    const int cw = w * 32;    // PV-phase c base

    for (int ic = 0; ic < 16; ++ic) {
        const int i0 = ibase + ic * 128;
        if (tid < 128) sl[tid] = log2f(l[(size_t)b * N_ + i0 + tid]);
        __syncthreads();   // sl ready; prev chunk's PV done -> sP free
        // ---- S phase ----
        {
            f32x4 sa[4];
#pragma unroll
            for (int nt = 0; nt < 4; ++nt) sa[nt] = (f32x4){0.f, 0.f, 0.f, 0.f};
            const size_t krow = ((size_t)(b * N_ + i0 + iw + c16)) * C_ + g * 8;
#pragma unroll
            for (int k = 0; k < 8; ++k) {
                bf16x8 av = ld_bf8(Kt + krow + k * 32);
#pragma unroll
                for (int nt = 0; nt < 4; ++nt) {
                    const int row = nt * 16 + c16;
                    bf16x8 bv = *(const bf16x8*)&sQ[row * 256 + (((k * 4 + g) ^ (c16 & 7)) * 8)];
                    sa[nt] = __builtin_amdgcn_mfma_f32_16x16x32_bf16(av, bv, sa[nt], 0, 0, 0);
                }
            }
            const float rv0 = sl[iw + g * 4 + 0];
            const float rv1 = sl[iw + g * 4 + 1];
            const float rv2 = sl[iw + g * 4 + 2];
            const float rv3 = sl[iw + g * 4 + 3];
            const int Cc = w * 2 + (g >> 1);          // 16B chunk of this uint2's i-range
#pragma unroll
            for (int nt = 0; nt < 4; ++nt) {
                const int j = nt * 16 + c16;
                unsigned p0 = f2bf(exp2f(sa[nt][0] - rv0));
                unsigned p1 = f2bf(exp2f(sa[nt][1] - rv1));
                unsigned p2 = f2bf(exp2f(sa[nt][2] - rv2));
                unsigned p3 = f2bf(exp2f(sa[nt][3] - rv3));
                uint2 pk; pk.x = p0 | (p1 << 16); pk.y = p2 | (p3 << 16);
                *(uint2*)&sP[j * 128 + ((Cc ^ (j & 7)) * 8 + (g & 1) * 4)] = pk;
            }
        }
        __syncthreads();   // sP ready
        // ---- PV phase ----
#pragma unroll
        for (int ks = 0; ks < 4; ++ks) {
            bf16x8 va[2];
#pragma unroll
            for (int mt = 0; mt < 2; ++mt)
                va[mt] = ld_bf8(V + ((size_t)(b * C_ + cw + mt * 16 + c16)) * N_ + i0 + ks * 32 + g * 8);
#pragma unroll
            for (int nt = 0; nt < 4; ++nt) {
                const int j = nt * 16 + c16;
                bf16x8 pb = *(const bf16x8*)&sP[j * 128 + (((ks * 4 + g) ^ (j & 7)) * 8)];
#pragma unroll
                for (int mt = 0; mt < 2; ++mt)
                    acc[mt][nt] = __builtin_amdgcn_mfma_f32_16x16x32_bf16(va[mt], pb, acc[mt][nt], 0, 0, 0);
            }
        }
    }
#pragma unroll
    for (int mt = 0; mt < 2; ++mt)
#pragma unroll
        for (int nt = 0; nt < 4; ++nt)
#pragma unroll
            for (int r = 0; r < 4; ++r) {
                const int c = cw + mt * 16 + g * 4 + r;
                const int j = jb + nt * 16 + c16;
                atomicAdd(dout + ((size_t)b * C_ + c) * N_ + j, acc[mt][nt][r]);
            }
}

extern "C" void kernel_launch(void* const* d_in, const int* in_sizes, int n_in,
                              void* d_out, int out_size, void* d_ws, size_t ws_size,
                              hipStream_t stream) {
    const float* x_s2  = (const float*)d_in[0];
    const float* x_dem = (const float*)d_in[1];
    const float* Wq = (const float*)d_in[2];
    const float* bq = (const float*)d_in[3];
    const float* Wk = (const float*)d_in[4];
    const float* bk = (const float*)d_in[5];
    const float* Wv = (const float*)d_in[6];
    const float* bv = (const float*)d_in[7];
    float* out = (float*)d_out;

    char* ws = (char*)d_ws;
    ushort_t* Qt = (ushort_t*)(ws);                               // [B][N][C] bf16, 8 MB
    ushort_t* Kt = (ushort_t*)(ws + (size_t)8  * 1024 * 1024);    // [B][N][C] bf16, pre-scaled
    ushort_t* Vm = (ushort_t*)(ws + (size_t)16 * 1024 * 1024);    // [B][C][N] bf16
    float*    lv = (float*)   (ws + (size_t)24 * 1024 * 1024);    // [B][N] row sums

    hipMemsetAsync(lv, 0, (size_t)B_ * N_ * sizeof(float), stream);
    // residual: pre-fill output with x_s2; out_kernel atomically adds O
    hipMemcpyAsync(out, x_s2, (size_t)B_ * C_ * N_ * sizeof(float),
                   hipMemcpyDeviceToDevice, stream);

    proj_t_kernel<<<dim3(N_ / 64, C_ / 64, B_), 256, 0, stream>>>(x_s2, Wq, bq, Qt, C_, 1.0f);
    proj_t_kernel<<<dim3(N_ / 64, C_ / 64, B_), 256, 0, stream>>>(x_dem, Wk, bk, Kt, CD_, SCALE_LOG2E);
    proj_n_kernel<<<dim3(N_ / 64, C_ / 64, B_), 256, 0, stream>>>(x_dem, Wv, bv, Vm, CD_);
    stats_kernel<<<dim3(N_ / 128, N_ / 128, B_), 256, 0, stream>>>(Kt, Qt, lv);
    out_kernel<<<dim3(N_ / 64, 2, B_), 512, 0, stream>>>(Kt, Qt, Vm, lv, out);
}